// Round 3
// baseline (562.266 us; speedup 1.0000x reference)
//
#include <hip/hip_runtime.h>
#include <hip/hip_bf16.h>

#define DEV __device__ __forceinline__

typedef short bf16x8 __attribute__((ext_vector_type(8)));
typedef short bf16x4 __attribute__((ext_vector_type(4)));
typedef float f32x4 __attribute__((ext_vector_type(4)));

static constexpr int B_  = 4;
static constexpr int S_  = 1024;
static constexpr int H_  = 1024;
static constexpr int NH_ = 16;
static constexpr int DH_ = 64;
static constexpr int BS_ = B_ * S_;   // 4096
static constexpr int H3_ = 3 * H_;    // 3072

// ---------------- async global->LDS (16B per lane) ----------------
DEV void gld16(const void* g, void* l) {
  __builtin_amdgcn_global_load_lds(
      (__attribute__((address_space(1))) void*)(unsigned long long)g,
      (__attribute__((address_space(3))) void*)(unsigned)(unsigned long long)l,
      16, 0, 0);
}

// 16x16x16 bf16 MFMA (A-frag layout matches C-layout of transposed scores)
DEV f32x4 pv_mfma(bf16x4 a, bf16x4 b, f32x4 c) {
#if __has_builtin(__builtin_amdgcn_mfma_f32_16x16x16bf16_1k)
  return __builtin_amdgcn_mfma_f32_16x16x16bf16_1k(a, b, c, 0, 0, 0);
#else
  asm volatile("v_mfma_f32_16x16x16_bf16 %0, %1, %2, %0" : "+v"(c) : "v"(a), "v"(b));
  return c;
#endif
}

// ---------------- reductions (blockDim == 256) ----------------
DEV float wred_sum(float v) {
#pragma unroll
  for (int o = 32; o; o >>= 1) v += __shfl_xor(v, o);
  return v;
}
DEV float bred_sum(float v, float* sh) {
  v = wred_sum(v);
  const int tid = threadIdx.x;
  if ((tid & 63) == 0) sh[tid >> 6] = v;
  __syncthreads();
  v = sh[0] + sh[1] + sh[2] + sh[3];
  __syncthreads();
  return v;
}
DEV float geluf(float x) { return 0.5f * x * (1.f + erff(x * 0.70710678118654752f)); }

// ---------------- fused casts: all fp32->bf16 staging in ONE dispatch ----------------
struct CastSeg { const float* src; unsigned short* dst; int nsrc; int ntot; };
struct CastArgs { CastSeg s[8]; };
__global__ __launch_bounds__(256) void castall_k(CastArgs a) {
  const CastSeg g = a.s[blockIdx.y];
  int i = (blockIdx.x * 256 + threadIdx.x) * 4;
  if (i >= g.ntot) return;
  float4 v;
  if (i + 4 <= g.nsrc) {
    v = *(const float4*)(g.src + i);
  } else {
    v.x = (i + 0 < g.nsrc) ? g.src[i + 0] : 0.f;
    v.y = (i + 1 < g.nsrc) ? g.src[i + 1] : 0.f;
    v.z = (i + 2 < g.nsrc) ? g.src[i + 2] : 0.f;
    v.w = (i + 3 < g.nsrc) ? g.src[i + 3] : 0.f;
  }
  __hip_bfloat16 o0 = __float2bfloat16(v.x), o1 = __float2bfloat16(v.y);
  __hip_bfloat16 o2 = __float2bfloat16(v.z), o3 = __float2bfloat16(v.w);
  ushort4 o;
  o.x = *(unsigned short*)&o0; o.y = *(unsigned short*)&o1;
  o.z = *(unsigned short*)&o2; o.w = *(unsigned short*)&o3;
  *(ushort4*)(g.dst + i) = o;
}

// ---------------- MFMA GEMM: C[M,N] = A[M,K] * W[N,K]^T ----------------
template <int MT, int NT, int WR, int WC, bool OBF>
__global__ __launch_bounds__(256) void gemm_bt(
    const __hip_bfloat16* __restrict__ Ap, const __hip_bfloat16* __restrict__ Wp,
    void* __restrict__ Cp, int K, int lda, int ldw, int ldc,
    long long szA, long long szW, long long szC) {
  constexpr int BM = WR * MT * 16;
  constexpr int BN = WC * NT * 16;
  constexpr int BK = 32;
  __shared__ __align__(16) short sA[BM * BK];
  __shared__ __align__(16) short sB[BN * BK];
  const int tid = threadIdx.x;
  const int wave = tid >> 6, lane = tid & 63;
  const int wm = wave / WC, wn = wave % WC;
  const int lr = lane & 15, kq = lane >> 4;
  const short* Ab = (const short*)Ap + blockIdx.z * szA + (long long)blockIdx.y * BM * lda;
  const short* Wb = (const short*)Wp + blockIdx.z * szW + (long long)blockIdx.x * BN * ldw;

  f32x4 acc[MT][NT];
#pragma unroll
  for (int i = 0; i < MT; i++)
#pragma unroll
    for (int j = 0; j < NT; j++) acc[i][j] = f32x4{0.f, 0.f, 0.f, 0.f};

  for (int k0 = 0; k0 < K; k0 += BK) {
#pragma unroll
    for (int r = 0; r < BM / 64; r++) {
      int idx = r * 256 + tid;
      const short* src = Ab + (long long)(idx >> 2) * lda + k0 + (idx & 3) * 8;
      gld16(src, sA + (size_t)idx * 8);
    }
#pragma unroll
    for (int r = 0; r < BN / 64; r++) {
      int idx = r * 256 + tid;
      const short* src = Wb + (long long)(idx >> 2) * ldw + k0 + (idx & 3) * 8;
      gld16(src, sB + (size_t)idx * 8);
    }
    __syncthreads();
    bf16x8 af[MT], bfr[NT];
#pragma unroll
    for (int i = 0; i < MT; i++)
      af[i] = *(const bf16x8*)(sA + (wm * MT * 16 + i * 16 + lr) * BK + kq * 8);
#pragma unroll
    for (int j = 0; j < NT; j++)
      bfr[j] = *(const bf16x8*)(sB + (wn * NT * 16 + j * 16 + lr) * BK + kq * 8);
#pragma unroll
    for (int i = 0; i < MT; i++)
#pragma unroll
      for (int j = 0; j < NT; j++)
        acc[i][j] = __builtin_amdgcn_mfma_f32_16x16x32_bf16(af[i], bfr[j], acc[i][j], 0, 0, 0);
    __syncthreads();
  }
  const long long row0 = (long long)blockIdx.y * BM + wm * MT * 16 + kq * 4;
  const long long col0 = (long long)blockIdx.x * BN + wn * NT * 16 + lr;
  const long long cb = blockIdx.z * szC;
#pragma unroll
  for (int i = 0; i < MT; i++)
#pragma unroll
    for (int j = 0; j < NT; j++)
#pragma unroll
      for (int r = 0; r < 4; r++) {
        long long off = cb + (row0 + i * 16 + r) * ldc + col0 + j * 16;
        if constexpr (OBF)
          ((__hip_bfloat16*)Cp)[off] = __float2bfloat16(acc[i][j][r]);
        else
          ((float*)Cp)[off] = acc[i][j][r];
      }
}

// ---------------- V transpose per head: vt[bh][d][s] = v[b,s,2H + h*64+d] ----------------
__global__ __launch_bounds__(256) void transpose_v_k(const __hip_bfloat16* __restrict__ qkv,
                                                     __hip_bfloat16* __restrict__ vt) {
  const int bh = blockIdx.y;
  const int b = bh >> 4, h = bh & 15;
  const int s0 = blockIdx.x << 6;
  __shared__ __hip_bfloat16 tile[64 * 65];
  const int tid = threadIdx.x;
  const __hip_bfloat16* src = qkv + ((size_t)(b * S_) + s0) * H3_ + 2 * H_ + h * DH_;
#pragma unroll
  for (int i = 0; i < 16; i++) {
    int idx = tid + i * 256;
    int rr = idx >> 6, cc = idx & 63;
    tile[cc * 65 + rr] = src[(size_t)rr * H3_ + cc];
  }
  __syncthreads();
  __hip_bfloat16* dst = vt + (size_t)bh * DH_ * S_ + s0;
#pragma unroll
  for (int i = 0; i < 16; i++) {
    int idx = tid + i * 256;
    int dd = idx >> 6, ss = idx & 63;
    dst[(size_t)dd * S_ + ss] = tile[dd * 65 + ss];
  }
}

// ---------------- fused flash attention ----------------
// grid = (bh=64, qb=8): XCD = bh%8 -> each XCD's blocks share 8 bh => K/V
// working set ~2MB, L2-resident. Q frags live in registers (loaded once from
// global). K/V staged via register prefetch double-buffer (latency hidden
// behind MFMA+softmax compute of the previous tile).
template <bool TTM>
__global__ __launch_bounds__(256) void flash_k(
    const __hip_bfloat16* __restrict__ qkv,   // [B,S,3H]
    const __hip_bfloat16* __restrict__ vt,    // [bh][DH][S]
    const float* __restrict__ twn,            // [B*S] or unused
    __hip_bfloat16* __restrict__ ctx,         // [B,S,H]
    float scale) {
  constexpr int LQ = 72;    // sK row stride (shorts)
  constexpr int LV = 136;   // sVT row stride (shorts)
  __shared__ __align__(16) short sK[128 * LQ];
  __shared__ __align__(16) short sVT[64 * LV];
  const int bh = blockIdx.x, b = bh >> 4, h = bh & 15;
  const int qb = blockIdx.y;  // 0..7
  const int tid = threadIdx.x, lane = tid & 63, wid = tid >> 6;
  const int lr = lane & 15, quad = lane >> 4;
  const short* qg = (const short*)qkv + ((size_t)(b * S_) + qb * 128) * H3_ + h * 64;
  const short* kg = (const short*)qkv + (size_t)b * S_ * H3_ + H_ + h * 64;
  const short* vg = (const short*)vt + (size_t)bh * DH_ * S_;

  // Q fragments straight from global (each wave reads only its own q rows)
  bf16x8 bq[2][2];
#pragma unroll
  for (int nt = 0; nt < 2; nt++)
#pragma unroll
    for (int kk = 0; kk < 2; kk++)
      bq[nt][kk] =
          *(const bf16x8*)(qg + (size_t)(wid * 32 + nt * 16 + lr) * H3_ + kk * 32 + quad * 8);

  float fs[2];
#pragma unroll
  for (int nt = 0; nt < 2; nt++) {
    int q = qb * 128 + wid * 32 + nt * 16 + lr;
    fs[nt] = TTM ? scale : scale * twn[b * S_ + q];
  }
  f32x4 O[2][4];
#pragma unroll
  for (int nt = 0; nt < 2; nt++)
#pragma unroll
    for (int dt = 0; dt < 4; dt++) O[nt][dt] = f32x4{0.f, 0.f, 0.f, 0.f};
  float mrow[2] = {-INFINITY, -INFINITY};
  float lrow[2] = {0.f, 0.f};

  // staging coords
  const int krow = tid >> 3, kc = tid & 7;   // K: 128 rows x 64 shorts
  const int vrow = tid >> 4, vc = tid & 15;  // VT: 64 rows x 128 shorts
  int4 kr[4], vr[4];
#pragma unroll
  for (int i = 0; i < 4; i++)
    kr[i] = *(const int4*)(kg + (size_t)(krow + i * 32) * H3_ + kc * 8);
#pragma unroll
  for (int i = 0; i < 4; i++)
    vr[i] = *(const int4*)(vg + (size_t)(vrow + i * 16) * S_ + vc * 8);

  for (int kt = 0; kt < 8; kt++) {
    if (kt) __syncthreads();
#pragma unroll
    for (int i = 0; i < 4; i++) *(int4*)(sK + (krow + i * 32) * LQ + kc * 8) = kr[i];
#pragma unroll
    for (int i = 0; i < 4; i++) *(int4*)(sVT + (vrow + i * 16) * LV + vc * 8) = vr[i];
    __syncthreads();
    if (kt < 7) {
#pragma unroll
      for (int i = 0; i < 4; i++)
        kr[i] = *(const int4*)(kg + (size_t)((kt + 1) * 128 + krow + i * 32) * H3_ + kc * 8);
#pragma unroll
      for (int i = 0; i < 4; i++)
        vr[i] = *(const int4*)(vg + (size_t)(vrow + i * 16) * S_ + (kt + 1) * 128 + vc * 8);
    }

    // ---- S^T tile: 128(s) x 32(q per wave) ----
    f32x4 Sa[8][2];
#pragma unroll
    for (int mt = 0; mt < 8; mt++)
#pragma unroll
      for (int nt = 0; nt < 2; nt++) Sa[mt][nt] = f32x4{0.f, 0.f, 0.f, 0.f};
#pragma unroll
    for (int mt = 0; mt < 8; mt++)
#pragma unroll
      for (int kk = 0; kk < 2; kk++) {
        bf16x8 ak = *(const bf16x8*)(sK + (mt * 16 + lr) * LQ + kk * 32 + quad * 8);
#pragma unroll
        for (int nt = 0; nt < 2; nt++)
          Sa[mt][nt] = __builtin_amdgcn_mfma_f32_16x16x32_bf16(ak, bq[nt][kk], Sa[mt][nt], 0, 0, 0);
      }

    // ---- online softmax per q column ----
    bf16x4 Pf[8][2];
#pragma unroll
    for (int nt = 0; nt < 2; nt++) {
      float mx = -INFINITY;
#pragma unroll
      for (int mt = 0; mt < 8; mt++)
#pragma unroll
        for (int r = 0; r < 4; r++) {
          Sa[mt][nt][r] *= fs[nt];
          mx = fmaxf(mx, Sa[mt][nt][r]);
        }
      mx = fmaxf(mx, __shfl_xor(mx, 16));
      mx = fmaxf(mx, __shfl_xor(mx, 32));
      const float mnew = fmaxf(mrow[nt], mx);
      const float al = __expf(mrow[nt] - mnew);
      mrow[nt] = mnew;
      float ls = 0.f;
#pragma unroll
      for (int mt = 0; mt < 8; mt++) {
        float p0 = __expf(Sa[mt][nt][0] - mnew);
        float p1 = __expf(Sa[mt][nt][1] - mnew);
        float p2 = __expf(Sa[mt][nt][2] - mnew);
        float p3 = __expf(Sa[mt][nt][3] - mnew);
        ls += (p0 + p1) + (p2 + p3);
        __hip_bfloat16 h0 = __float2bfloat16(p0), h1 = __float2bfloat16(p1);
        __hip_bfloat16 h2 = __float2bfloat16(p2), h3 = __float2bfloat16(p3);
        bf16x4 pk;
        pk[0] = *(short*)&h0; pk[1] = *(short*)&h1;
        pk[2] = *(short*)&h2; pk[3] = *(short*)&h3;
        Pf[mt][nt] = pk;
      }
      ls += __shfl_xor(ls, 16);
      ls += __shfl_xor(ls, 32);
      lrow[nt] = lrow[nt] * al + ls;
#pragma unroll
      for (int r = 0; r < 4; r++) {
        float ar = __shfl(al, quad * 4 + r);
#pragma unroll
        for (int dt = 0; dt < 4; dt++) O[nt][dt][r] *= ar;
      }
    }

    // ---- O += P·V via 16x16x16 (P^T regs are A-frags directly) ----
#pragma unroll
    for (int mt = 0; mt < 8; mt++)
#pragma unroll
      for (int dt = 0; dt < 4; dt++) {
        bf16x4 bv = *(const bf16x4*)(sVT + (dt * 16 + lr) * LV + mt * 16 + quad * 4);
#pragma unroll
        for (int nt = 0; nt < 2; nt++) O[nt][dt] = pv_mfma(Pf[mt][nt], bv, O[nt][dt]);
      }
  }

  // ---- epilogue: O /= l, store ----
#pragma unroll
  for (int nt = 0; nt < 2; nt++)
#pragma unroll
    for (int r = 0; r < 4; r++) {
      float li = __shfl(lrow[nt], quad * 4 + r);
      float inv = 1.f / li;
      int q = qb * 128 + wid * 32 + nt * 16 + quad * 4 + r;
      __hip_bfloat16* op = ctx + ((size_t)(b * S_) + q) * H_ + h * 64 + lr;
#pragma unroll
      for (int dt = 0; dt < 4; dt++)
        op[dt * 16] = __float2bfloat16(O[nt][dt][r] * inv);
    }
}

// ---------------- fused wt-proj (N=16) + LN + sigmoid -> T0 ----------------
// block = 16 rows; thread (r=tid>>4, n=tid&15) computes dot(to[bs,:], wt[n,:])
__global__ __launch_bounds__(256) void wtln_k(const __hip_bfloat16* __restrict__ to,
                                              const float* __restrict__ wt,
                                              const float* __restrict__ g,
                                              const float* __restrict__ be,
                                              float* __restrict__ T0) {
  const int tid = threadIdx.x;
  const int r = tid >> 4, n = tid & 15;
  const int bs = blockIdx.x * 16 + r;
  const __hip_bfloat16* trow = to + (size_t)bs * H_;
  const float* wrow = wt + (size_t)n * H_;
  float acc = 0.f;
  for (int k = 0; k < H_; k += 8) {
    bf16x8 t8 = *(const bf16x8*)(trow + k);
    float4 w0 = *(const float4*)(wrow + k);
    float4 w1 = *(const float4*)(wrow + k + 4);
    __hip_bfloat16 tv;
#pragma unroll
    for (int j = 0; j < 4; j++) {
      short s0 = t8[j];
      tv = *(__hip_bfloat16*)&s0;
      acc += __bfloat162float(tv) * (&w0.x)[j];
    }
#pragma unroll
    for (int j = 0; j < 4; j++) {
      short s1 = t8[4 + j];
      tv = *(__hip_bfloat16*)&s1;
      acc += __bfloat162float(tv) * (&w1.x)[j];
    }
  }
  float mean = acc;
#pragma unroll
  for (int o = 1; o < 16; o <<= 1) mean += __shfl_xor(mean, o);
  mean *= (1.f / 16.f);
  float d = acc - mean;
  float var = d * d;
#pragma unroll
  for (int o = 1; o < 16; o <<= 1) var += __shfl_xor(var, o);
  var *= (1.f / 16.f);
  float z = d * rsqrtf(var + 1e-5f) * g[n] + be[n];
  float t = 1.f / (1.f + expf(-z));
  T0[(size_t)bs * 16 + n] = 1.f + 0.1f * (t - 0.5f);
}

// ---------------- thp: sigmoid(gelu(LN(T0 @ thp_w^T + b))) ----------------
__global__ __launch_bounds__(256) void thp_k(const float* __restrict__ T0,
                                             const float* __restrict__ w,
                                             const float* __restrict__ bb,
                                             const float* __restrict__ g,
                                             const float* __restrict__ be,
                                             __hip_bfloat16* __restrict__ Tb,
                                             float* __restrict__ t0out) {
  __shared__ float sh[4];
  __shared__ float t0s[16];
  const int bs = blockIdx.x, tid = threadIdx.x;
  if (tid < 16) t0s[tid] = T0[(size_t)bs * 16 + tid];
  __syncthreads();
  float y[4];
#pragma unroll
  for (int i = 0; i < 4; i++) {
    int hh = tid + i * 256;
    const float* wr = w + (size_t)hh * 16;
    float a = bb[hh];
#pragma unroll
    for (int n = 0; n < 16; n++) a += t0s[n] * wr[n];
    y[i] = a;
  }
  float mean = bred_sum(y[0] + y[1] + y[2] + y[3], sh) * (1.f / 1024.f);
  float q = 0.f;
#pragma unroll
  for (int i = 0; i < 4; i++) { float d = y[i] - mean; q += d * d; }
  float var = bred_sum(q, sh) * (1.f / 1024.f);
  const float rs = rsqrtf(var + 1e-5f);
#pragma unroll
  for (int i = 0; i < 4; i++) {
    int hh = tid + i * 256;
    float z = (y[i] - mean) * rs * g[hh] + be[hh];
    float t = 1.f / (1.f + expf(-geluf(z)));
    Tb[(size_t)bs * H_ + hh] = __float2bfloat16(t);
    if (hh == 0) t0out[bs] = t;
  }
}

// ---------------- rowsum of W1b (fp32 exact) ----------------
__global__ __launch_bounds__(256) void rowsum_k(const float* __restrict__ w1,
                                                float* __restrict__ rs) {
  const int tid = threadIdx.x;
  const int row = blockIdx.x * 4 + (tid >> 6);
  const int lane = tid & 63;
  float s = 0.f;
#pragma unroll
  for (int j = 0; j < 16; j++) s += w1[(size_t)row * 2048 + 1024 + lane + j * 64];
  s = wred_sum(s);
  if (lane == 0) rs[row] = s;
}

// ---------------- fused: h = gelu(LN(...)); Ti = sig(sig(h.w2 + b2)) ----------------
__global__ __launch_bounds__(256) void hlnrd_k(const float* __restrict__ xa,
                                               const float* __restrict__ addm,
                                               const float* __restrict__ Ti,
                                               const float* __restrict__ rsum,
                                               const float* __restrict__ b1,
                                               const float* __restrict__ g,
                                               const float* __restrict__ be,
                                               const float* __restrict__ w2,
                                               const float* __restrict__ b2,
                                               float* __restrict__ tout, int mode) {
  __shared__ float sh[4];
  const int bs = blockIdx.x, tid = threadIdx.x;
  const float tv = mode ? Ti[bs] : 0.f;
  float y[4];
#pragma unroll
  for (int i = 0; i < 4; i++) {
    int hh = tid + i * 256;
    float add = mode ? tv * rsum[hh] : addm[(size_t)bs * H_ + hh];
    y[i] = xa[(size_t)bs * H_ + hh] + add + b1[hh];
  }
  float mean = bred_sum(y[0] + y[1] + y[2] + y[3], sh) * (1.f / 1024.f);
  float q = 0.f;
#pragma unroll
  for (int i = 0; i < 4; i++) { float d = y[i] - mean; q += d * d; }
  float var = bred_sum(q, sh) * (1.f / 1024.f);
  const float rs = rsqrtf(var + 1e-5f);
  float s = 0.f;
#pragma unroll
  for (int i = 0; i < 4; i++) {
    int hh = tid + i * 256;
    float z = (y[i] - mean) * rs * g[hh] + be[hh];
    s += geluf(z) * w2[hh];
  }
  s = bred_sum(s, sh);
  if (tid == 0) {
    float d = s + b2[0];
    float t = 1.f / (1.f + expf(-d));
    t = 1.f / (1.f + expf(-t));
    tout[bs] = t;
  }
}

// ---------------- global stats -> twn; also emits scale_temps output ----------------
__global__ __launch_bounds__(256) void stats_k(const float* __restrict__ t0,
                                               const float* __restrict__ t1,
                                               const float* __restrict__ t2,
                                               float* __restrict__ twn,
                                               float* __restrict__ out2) {
  __shared__ float sh[4];
  const int tid = threadIdx.x;
  float s = 0.f;
  for (int i = tid; i < BS_; i += 256) s += (t0[i] + t1[i] + t2[i]) * (1.f / 3.f);
  const float mu = bred_sum(s, sh) * (1.f / (float)BS_);
  float q = 0.f;
  for (int i = tid; i < BS_; i += 256) {
    float tw = (t0[i] + t1[i] + t2[i]) * (1.f / 3.f);
    float d = tw - mu;
    q += d * d;
  }
  const float var = bred_sum(q, sh) * (1.f / (float)BS_);
  const float stdu = sqrtf(var);
  const float inv = 1.f / (stdu + 1.1920929e-07f);
  for (int i = tid; i < BS_; i += 256) {
    float tw = (t0[i] + t1[i] + t2[i]) * (1.f / 3.f);
    twn[i] = 1.f + (tw - mu) * inv;
  }
  for (int i = tid; i < 3 * BS_; i += 256) {  // [B,3,S,1]
    int b = i / 3072, r = i - b * 3072;
    int j = r >> 10, ss = r & 1023;
    const float* tp = (j == 0) ? t0 : ((j == 1) ? t1 : t2);
    out2[i] = tp[b * S_ + ss];
  }
}

// =====================================================================
extern "C" void kernel_launch(void* const* d_in, const int* in_sizes, int n_in,
                              void* d_out, int out_size, void* d_ws, size_t ws_size,
                              hipStream_t stream) {
  (void)in_sizes; (void)n_in; (void)out_size; (void)ws_size;
  const float* x     = (const float*)d_in[0];
  const float* wq    = (const float*)d_in[1];
  const float* wk    = (const float*)d_in[2];
  const float* wv    = (const float*)d_in[3];
  const float* wo    = (const float*)d_in[4];
  const float* w_in  = (const float*)d_in[5];
  const float* w_out = (const float*)d_in[6];
  const float* wt    = (const float*)d_in[7];
  const float* ttm_g = (const float*)d_in[8];
  const float* ttm_b = (const float*)d_in[9];
  const float* thp_w = (const float*)d_in[10];
  const float* thp_b = (const float*)d_in[11];
  const float* thp_g = (const float*)d_in[12];
  const float* thp_e = (const float*)d_in[13];
  const float* w1    = (const float*)d_in[14];
  const float* b1    = (const float*)d_in[15];
  const float* tn_g  = (const float*)d_in[16];
  const float* tn_e  = (const float*)d_in[17];
  const float* w2    = (const float*)d_in[18];
  const float* b2    = (const float*)d_in[19];

  char* ws = (char*)d_ws;
  size_t off = 0;
  auto alloc = [&](size_t bytes) {
    void* p = ws + off;
    off = (off + bytes + 255) & ~(size_t)255;
    return p;
  };

  __hip_bfloat16* xb    = (__hip_bfloat16*)alloc((size_t)BS_ * H_ * 2);
  __hip_bfloat16* winb  = (__hip_bfloat16*)alloc((size_t)H3_ * H_ * 2);
  __hip_bfloat16* woutb = (__hip_bfloat16*)alloc((size_t)H_ * H_ * 2);
  __hip_bfloat16* wqkvb = (__hip_bfloat16*)alloc((size_t)H3_ * H_ * 2);
  __hip_bfloat16* wob   = (__hip_bfloat16*)alloc((size_t)H_ * H_ * 2);
  __hip_bfloat16* w1b   = (__hip_bfloat16*)alloc((size_t)H_ * 2 * H_ * 2);
  __hip_bfloat16* qkvb  = (__hip_bfloat16*)alloc((size_t)BS_ * H3_ * 2);
  __hip_bfloat16* vtb   = (__hip_bfloat16*)alloc((size_t)64 * DH_ * S_ * 2);
  __hip_bfloat16* mctxb = (__hip_bfloat16*)alloc((size_t)BS_ * H_ * 2);
  __hip_bfloat16* tob   = (__hip_bfloat16*)alloc((size_t)BS_ * H_ * 2);
  float* T0    = (float*)alloc((size_t)BS_ * NH_ * 4);
  float* xw1a  = (float*)alloc((size_t)BS_ * H_ * 4);
  float* tbw   = (float*)alloc((size_t)BS_ * H_ * 4);
  float* temps = (float*)alloc((size_t)3 * BS_ * 4);
  float* twn   = (float*)alloc((size_t)BS_ * 4);
  float* rsum  = (float*)alloc((size_t)H_ * 4);

  const float scale = 0.125f;  // DH^-0.5
  dim3 blk(256);

  // ---- all casts in one dispatch ----
  CastArgs ca;
  ca.s[0] = {x, (unsigned short*)xb, BS_ * H_, BS_ * H_};
  ca.s[1] = {w_in, (unsigned short*)winb, H3_ * H_, H3_ * H_};
  ca.s[2] = {w_out, (unsigned short*)woutb, H_ * H_, H_ * H_};
  ca.s[3] = {wq, (unsigned short*)wqkvb, H_ * H_, H_ * H_};
  ca.s[4] = {wk, (unsigned short*)wqkvb + (size_t)H_ * H_, H_ * H_, H_ * H_};
  ca.s[5] = {wv, (unsigned short*)wqkvb + (size_t)2 * H_ * H_, H_ * H_, H_ * H_};
  ca.s[6] = {wo, (unsigned short*)wob, H_ * H_, H_ * H_};
  ca.s[7] = {w1, (unsigned short*)w1b, 2 * H_ * H_, 2 * H_ * H_};
  castall_k<<<dim3((BS_ * H_ + 1023) / 1024, 8), blk, 0, stream>>>(ca);
  rowsum_k<<<H_ / 4, blk, 0, stream>>>(w1, rsum);

  // ---- ttm MHA ----
  gemm_bt<4, 4, 2, 2, true><<<dim3(H3_ / 128, BS_ / 128, 1), blk, 0, stream>>>(
      xb, winb, qkvb, H_, H_, H_, H3_, 0, 0, 0);
  transpose_v_k<<<dim3(S_ / 64, 64), blk, 0, stream>>>(qkvb, vtb);
  flash_k<true><<<dim3(64, 8), blk, 0, stream>>>(qkvb, vtb, (const float*)nullptr, mctxb, scale);
  gemm_bt<4, 4, 2, 2, true><<<dim3(H_ / 128, BS_ / 128, 1), blk, 0, stream>>>(
      mctxb, woutb, tob, H_, H_, H_, H_, 0, 0, 0);
  wtln_k<<<BS_ / 16, blk, 0, stream>>>(tob, wt, ttm_g, ttm_b, T0);
  thp_k<<<BS_, blk, 0, stream>>>(T0, thp_w, thp_b, thp_g, thp_e, tob, temps);

  // ---- temp_net (algebraic split of comb @ W1^T) ----
  gemm_bt<4, 4, 2, 2, false><<<dim3(H_ / 128, BS_ / 128, 1), blk, 0, stream>>>(
      xb, w1b, xw1a, H_, H_, 2 * H_, H_, 0, 0, 0);
  gemm_bt<4, 4, 2, 2, false><<<dim3(H_ / 128, BS_ / 128, 1), blk, 0, stream>>>(
      tob, w1b + H_, tbw, H_, H_, 2 * H_, H_, 0, 0, 0);
  hlnrd_k<<<BS_, blk, 0, stream>>>(xw1a, tbw, (const float*)nullptr, rsum, b1, tn_g, tn_e,
                                   w2, b2, temps + BS_, 0);
  hlnrd_k<<<BS_, blk, 0, stream>>>(xw1a, (const float*)nullptr, temps + BS_, rsum, b1, tn_g,
                                   tn_e, w2, b2, temps + 2 * BS_, 1);
  stats_k<<<1, blk, 0, stream>>>(temps, temps + BS_, temps + 2 * BS_, twn,
                                 (float*)d_out + (size_t)BS_ * H_);

  // ---- main attention ----
  gemm_bt<4, 4, 2, 2, true><<<dim3(H3_ / 128, BS_ / 128, 1), blk, 0, stream>>>(
      xb, wqkvb, qkvb, H_, H_, H_, H3_, 0, 0, 0);
  transpose_v_k<<<dim3(S_ / 64, 64), blk, 0, stream>>>(qkvb, vtb);
  flash_k<false><<<dim3(64, 8), blk, 0, stream>>>(qkvb, vtb, twn, mctxb, scale);
  gemm_bt<4, 4, 2, 2, false><<<dim3(H_ / 128, BS_ / 128, 1), blk, 0, stream>>>(
      mctxb, wob, (float*)d_out, H_, H_, H_, H_, 0, 0, 0);
}

// Round 4
// 519.001 us; speedup vs baseline: 1.0834x; 1.0834x over previous
//
#include <hip/hip_runtime.h>
#include <hip/hip_bf16.h>

#define DEV __device__ __forceinline__

typedef short bf16x8 __attribute__((ext_vector_type(8)));
typedef short bf16x4 __attribute__((ext_vector_type(4)));
typedef float f32x4 __attribute__((ext_vector_type(4)));

static constexpr int B_  = 4;
static constexpr int S_  = 1024;
static constexpr int H_  = 1024;
static constexpr int NH_ = 16;
static constexpr int DH_ = 64;
static constexpr int BS_ = B_ * S_;   // 4096
static constexpr int H3_ = 3 * H_;    // 3072

// ---------------- async global->LDS (16B per lane) ----------------
DEV void gld16(const void* g, void* l) {
  __builtin_amdgcn_global_load_lds(
      (__attribute__((address_space(1))) void*)(unsigned long long)g,
      (__attribute__((address_space(3))) void*)(unsigned)(unsigned long long)l,
      16, 0, 0);
}

// 16x16x16 bf16 MFMA (A-frag layout matches C-layout of transposed scores)
DEV f32x4 pv_mfma(bf16x4 a, bf16x4 b, f32x4 c) {
#if __has_builtin(__builtin_amdgcn_mfma_f32_16x16x16bf16_1k)
  return __builtin_amdgcn_mfma_f32_16x16x16bf16_1k(a, b, c, 0, 0, 0);
#else
  asm volatile("v_mfma_f32_16x16x16_bf16 %0, %1, %2, %0" : "+v"(c) : "v"(a), "v"(b));
  return c;
#endif
}

// ---------------- reductions (blockDim == 256) ----------------
DEV float wred_sum(float v) {
#pragma unroll
  for (int o = 32; o; o >>= 1) v += __shfl_xor(v, o);
  return v;
}
DEV float bred_sum(float v, float* sh) {
  v = wred_sum(v);
  const int tid = threadIdx.x;
  if ((tid & 63) == 0) sh[tid >> 6] = v;
  __syncthreads();
  v = sh[0] + sh[1] + sh[2] + sh[3];
  __syncthreads();
  return v;
}
DEV float geluf(float x) { return 0.5f * x * (1.f + erff(x * 0.70710678118654752f)); }

// ---------------- fused casts: all fp32->bf16 staging in ONE dispatch ----------------
struct CastSeg { const float* src; unsigned short* dst; int nsrc; int ntot; };
struct CastArgs { CastSeg s[8]; };
__global__ __launch_bounds__(256) void castall_k(CastArgs a) {
  const CastSeg g = a.s[blockIdx.y];
  int i = (blockIdx.x * 256 + threadIdx.x) * 4;
  if (i >= g.ntot) return;
  float4 v;
  if (i + 4 <= g.nsrc) {
    v = *(const float4*)(g.src + i);
  } else {
    v.x = (i + 0 < g.nsrc) ? g.src[i + 0] : 0.f;
    v.y = (i + 1 < g.nsrc) ? g.src[i + 1] : 0.f;
    v.z = (i + 2 < g.nsrc) ? g.src[i + 2] : 0.f;
    v.w = (i + 3 < g.nsrc) ? g.src[i + 3] : 0.f;
  }
  __hip_bfloat16 o0 = __float2bfloat16(v.x), o1 = __float2bfloat16(v.y);
  __hip_bfloat16 o2 = __float2bfloat16(v.z), o3 = __float2bfloat16(v.w);
  ushort4 o;
  o.x = *(unsigned short*)&o0; o.y = *(unsigned short*)&o1;
  o.z = *(unsigned short*)&o2; o.w = *(unsigned short*)&o3;
  *(ushort4*)(g.dst + i) = o;
}

// ---------------- MFMA GEMM: C[M,N] = A[M,K] * W[N,K]^T ----------------
template <int MT, int NT, int WR, int WC, bool OBF>
__global__ __launch_bounds__(256) void gemm_bt(
    const __hip_bfloat16* __restrict__ Ap, const __hip_bfloat16* __restrict__ Wp,
    void* __restrict__ Cp, int K, int lda, int ldw, int ldc,
    long long szA, long long szW, long long szC) {
  constexpr int BM = WR * MT * 16;
  constexpr int BN = WC * NT * 16;
  constexpr int BK = 32;
  __shared__ __align__(16) short sA[BM * BK];
  __shared__ __align__(16) short sB[BN * BK];
  const int tid = threadIdx.x;
  const int wave = tid >> 6, lane = tid & 63;
  const int wm = wave / WC, wn = wave % WC;
  const int lr = lane & 15, kq = lane >> 4;
  const short* Ab = (const short*)Ap + blockIdx.z * szA + (long long)blockIdx.y * BM * lda;
  const short* Wb = (const short*)Wp + blockIdx.z * szW + (long long)blockIdx.x * BN * ldw;

  f32x4 acc[MT][NT];
#pragma unroll
  for (int i = 0; i < MT; i++)
#pragma unroll
    for (int j = 0; j < NT; j++) acc[i][j] = f32x4{0.f, 0.f, 0.f, 0.f};

  for (int k0 = 0; k0 < K; k0 += BK) {
#pragma unroll
    for (int r = 0; r < BM / 64; r++) {
      int idx = r * 256 + tid;
      const short* src = Ab + (long long)(idx >> 2) * lda + k0 + (idx & 3) * 8;
      gld16(src, sA + (size_t)idx * 8);
    }
#pragma unroll
    for (int r = 0; r < BN / 64; r++) {
      int idx = r * 256 + tid;
      const short* src = Wb + (long long)(idx >> 2) * ldw + k0 + (idx & 3) * 8;
      gld16(src, sB + (size_t)idx * 8);
    }
    __syncthreads();
    bf16x8 af[MT], bfr[NT];
#pragma unroll
    for (int i = 0; i < MT; i++)
      af[i] = *(const bf16x8*)(sA + (wm * MT * 16 + i * 16 + lr) * BK + kq * 8);
#pragma unroll
    for (int j = 0; j < NT; j++)
      bfr[j] = *(const bf16x8*)(sB + (wn * NT * 16 + j * 16 + lr) * BK + kq * 8);
#pragma unroll
    for (int i = 0; i < MT; i++)
#pragma unroll
      for (int j = 0; j < NT; j++)
        acc[i][j] = __builtin_amdgcn_mfma_f32_16x16x32_bf16(af[i], bfr[j], acc[i][j], 0, 0, 0);
    __syncthreads();
  }
  const long long row0 = (long long)blockIdx.y * BM + wm * MT * 16 + kq * 4;
  const long long col0 = (long long)blockIdx.x * BN + wn * NT * 16 + lr;
  const long long cb = blockIdx.z * szC;
#pragma unroll
  for (int i = 0; i < MT; i++)
#pragma unroll
    for (int j = 0; j < NT; j++)
#pragma unroll
      for (int r = 0; r < 4; r++) {
        long long off = cb + (row0 + i * 16 + r) * ldc + col0 + j * 16;
        if constexpr (OBF)
          ((__hip_bfloat16*)Cp)[off] = __float2bfloat16(acc[i][j][r]);
        else
          ((float*)Cp)[off] = acc[i][j][r];
      }
}

// ---------------- V transpose per head: vt[bh][d][s] = v[b,s,2H + h*64+d] ----------------
__global__ __launch_bounds__(256) void transpose_v_k(const __hip_bfloat16* __restrict__ qkv,
                                                     __hip_bfloat16* __restrict__ vt) {
  const int bh = blockIdx.y;
  const int b = bh >> 4, h = bh & 15;
  const int s0 = blockIdx.x << 6;
  __shared__ short tile[64 * 65];
  const int tid = threadIdx.x;
  const short* src = (const short*)qkv + ((size_t)(b * S_) + s0) * H3_ + 2 * H_ + h * DH_;
#pragma unroll
  for (int i = 0; i < 4; i++) {
    int idx = tid + i * 256;
    int rr = idx >> 4, c4 = (idx & 15) * 4;
    short4 v = *(const short4*)(src + (size_t)rr * H3_ + c4);
    tile[(c4 + 0) * 65 + rr] = v.x;
    tile[(c4 + 1) * 65 + rr] = v.y;
    tile[(c4 + 2) * 65 + rr] = v.z;
    tile[(c4 + 3) * 65 + rr] = v.w;
  }
  __syncthreads();
  short* dst = (short*)vt + (size_t)bh * DH_ * S_ + s0;
#pragma unroll
  for (int i = 0; i < 4; i++) {
    int idx = tid + i * 256;
    int dd = idx >> 4, s4 = (idx & 15) * 4;
    short4 o;
    o.x = tile[dd * 65 + s4 + 0];
    o.y = tile[dd * 65 + s4 + 1];
    o.z = tile[dd * 65 + s4 + 2];
    o.w = tile[dd * 65 + s4 + 3];
    *(short4*)(dst + (size_t)dd * S_ + s4) = o;
  }
}

// ---------------- fused flash attention ----------------
// grid = (bh=64, qb=8): XCD = bh%8 -> per-XCD K/V working set ~2MB (L2-hit).
// K/V staged via global_load_lds into double-buffered LDS (no VGPR cost, no
// spill). Bank conflicts broken by 16B-chunk XOR swizzle applied on the
// GLOBAL address (LDS side of global_load_lds must stay linear in lane).
template <bool TTM>
__global__ __launch_bounds__(256) void flash_k(
    const __hip_bfloat16* __restrict__ qkv,   // [B,S,3H]
    const __hip_bfloat16* __restrict__ vt,    // [bh][DH][S]
    const float* __restrict__ twn,            // [B*S] or unused
    __hip_bfloat16* __restrict__ ctx,         // [B,S,H]
    float scale) {
  __shared__ __align__(16) short sK[2][128 * 64];   // 16 KB x2, swizzled
  __shared__ __align__(16) short sVT[2][64 * 128];  // 16 KB x2, swizzled
  const int bh = blockIdx.x, b = bh >> 4, h = bh & 15;
  const int qb = blockIdx.y;  // 0..7
  const int tid = threadIdx.x, lane = tid & 63, wid = tid >> 6;
  const int lr = lane & 15, quad = lane >> 4;
  const short* qg = (const short*)qkv + ((size_t)(b * S_) + qb * 128) * H3_ + h * 64;
  const short* kg = (const short*)qkv + (size_t)b * S_ * H3_ + H_ + h * 64;
  const short* vg = (const short*)vt + (size_t)bh * DH_ * S_;

  // staging: issue async loads for K-tile kt into buffer buf
  auto stage = [&](int kt, int buf) {
#pragma unroll
    for (int i = 0; i < 4; i++) {
      int idx = i * 256 + tid;
      int row = idx >> 3, cp = idx & 7;
      int c = cp ^ (row & 7);  // global chunk for LDS slot (row, cp)
      gld16(kg + (size_t)(kt * 128 + row) * H3_ + c * 8, &sK[buf][(size_t)idx * 8]);
    }
#pragma unroll
    for (int i = 0; i < 4; i++) {
      int idx = i * 256 + tid;
      int row = idx >> 4, cp = idx & 15;
      int c = cp ^ (row & 15);
      gld16(vg + (size_t)row * S_ + kt * 128 + c * 8, &sVT[buf][(size_t)idx * 8]);
    }
  };

  // Q fragments straight from global (each wave reads only its own q rows)
  bf16x8 bq[2][2];
#pragma unroll
  for (int nt = 0; nt < 2; nt++)
#pragma unroll
    for (int kk = 0; kk < 2; kk++)
      bq[nt][kk] =
          *(const bf16x8*)(qg + (size_t)(wid * 32 + nt * 16 + lr) * H3_ + kk * 32 + quad * 8);

  float fs[2];
#pragma unroll
  for (int nt = 0; nt < 2; nt++) {
    int q = qb * 128 + wid * 32 + nt * 16 + lr;
    fs[nt] = TTM ? scale : scale * twn[b * S_ + q];
  }
  f32x4 O[2][4];
#pragma unroll
  for (int nt = 0; nt < 2; nt++)
#pragma unroll
    for (int dt = 0; dt < 4; dt++) O[nt][dt] = f32x4{0.f, 0.f, 0.f, 0.f};
  float mrow[2] = {-INFINITY, -INFINITY};
  float lrow[2] = {0.f, 0.f};

  stage(0, 0);
  __syncthreads();  // drains vmcnt(0): buffer 0 ready

  for (int kt = 0; kt < 8; kt++) {
    const int cur = kt & 1;
    if (kt < 7) stage(kt + 1, cur ^ 1);  // async; completes at the barrier below
    const short* sKc = sK[cur];
    const short* sVc = sVT[cur];

    // ---- S^T tile: 128(s) x 32(q per wave) ----
    f32x4 Sa[8][2];
#pragma unroll
    for (int mt = 0; mt < 8; mt++)
#pragma unroll
      for (int nt = 0; nt < 2; nt++) Sa[mt][nt] = f32x4{0.f, 0.f, 0.f, 0.f};
#pragma unroll
    for (int mt = 0; mt < 8; mt++)
#pragma unroll
      for (int kk = 0; kk < 2; kk++) {
        int row = mt * 16 + lr;
        int cp = (kk * 4 + quad) ^ (lr & 7);
        bf16x8 ak = *(const bf16x8*)(sKc + row * 64 + cp * 8);
#pragma unroll
        for (int nt = 0; nt < 2; nt++)
          Sa[mt][nt] = __builtin_amdgcn_mfma_f32_16x16x32_bf16(ak, bq[nt][kk], Sa[mt][nt], 0, 0, 0);
      }

    // ---- online softmax per q column ----
    bf16x4 Pf[8][2];
#pragma unroll
    for (int nt = 0; nt < 2; nt++) {
      float mx = -INFINITY;
#pragma unroll
      for (int mt = 0; mt < 8; mt++)
#pragma unroll
        for (int r = 0; r < 4; r++) {
          Sa[mt][nt][r] *= fs[nt];
          mx = fmaxf(mx, Sa[mt][nt][r]);
        }
      mx = fmaxf(mx, __shfl_xor(mx, 16));
      mx = fmaxf(mx, __shfl_xor(mx, 32));
      const float mnew = fmaxf(mrow[nt], mx);
      const float al = __expf(mrow[nt] - mnew);
      mrow[nt] = mnew;
      float ls = 0.f;
#pragma unroll
      for (int mt = 0; mt < 8; mt++) {
        float p0 = __expf(Sa[mt][nt][0] - mnew);
        float p1 = __expf(Sa[mt][nt][1] - mnew);
        float p2 = __expf(Sa[mt][nt][2] - mnew);
        float p3 = __expf(Sa[mt][nt][3] - mnew);
        ls += (p0 + p1) + (p2 + p3);
        __hip_bfloat16 h0 = __float2bfloat16(p0), h1 = __float2bfloat16(p1);
        __hip_bfloat16 h2 = __float2bfloat16(p2), h3 = __float2bfloat16(p3);
        bf16x4 pk;
        pk[0] = *(short*)&h0; pk[1] = *(short*)&h1;
        pk[2] = *(short*)&h2; pk[3] = *(short*)&h3;
        Pf[mt][nt] = pk;
      }
      ls += __shfl_xor(ls, 16);
      ls += __shfl_xor(ls, 32);
      lrow[nt] = lrow[nt] * al + ls;
#pragma unroll
      for (int r = 0; r < 4; r++) {
        float ar = __shfl(al, quad * 4 + r);
#pragma unroll
        for (int dt = 0; dt < 4; dt++) O[nt][dt][r] *= ar;
      }
    }

    // ---- O += P·V via 16x16x16 (P^T regs are A-frags directly) ----
#pragma unroll
    for (int mt = 0; mt < 8; mt++)
#pragma unroll
      for (int dt = 0; dt < 4; dt++) {
        int row = dt * 16 + lr;
        int cp = (2 * mt + (quad >> 1)) ^ lr;  // row&15 == lr
        bf16x4 bv = *(const bf16x4*)(sVc + row * 128 + cp * 8 + (quad & 1) * 4);
#pragma unroll
        for (int nt = 0; nt < 2; nt++) O[nt][dt] = pv_mfma(Pf[mt][nt], bv, O[nt][dt]);
      }

    __syncthreads();  // all waves done with cur; staging of cur^1 drained
  }

  // ---- epilogue: O /= l, store ----
#pragma unroll
  for (int nt = 0; nt < 2; nt++)
#pragma unroll
    for (int r = 0; r < 4; r++) {
      float li = __shfl(lrow[nt], quad * 4 + r);
      float inv = 1.f / li;
      int q = qb * 128 + wid * 32 + nt * 16 + quad * 4 + r;
      __hip_bfloat16* op = ctx + ((size_t)(b * S_) + q) * H_ + h * 64 + lr;
#pragma unroll
      for (int dt = 0; dt < 4; dt++)
        op[dt * 16] = __float2bfloat16(O[nt][dt][r] * inv);
    }
}

// ---------------- fused wt-proj (N=16) + LN + sigmoid -> T0 ----------------
__global__ __launch_bounds__(256) void wtln_k(const __hip_bfloat16* __restrict__ to,
                                              const float* __restrict__ wt,
                                              const float* __restrict__ g,
                                              const float* __restrict__ be,
                                              float* __restrict__ T0) {
  const int tid = threadIdx.x;
  const int r = tid >> 4, n = tid & 15;
  const int bs = blockIdx.x * 16 + r;
  const __hip_bfloat16* trow = to + (size_t)bs * H_;
  const float* wrow = wt + (size_t)n * H_;
  float acc = 0.f;
  for (int k = 0; k < H_; k += 8) {
    bf16x8 t8 = *(const bf16x8*)(trow + k);
    float4 w0 = *(const float4*)(wrow + k);
    float4 w1 = *(const float4*)(wrow + k + 4);
    __hip_bfloat16 tv;
#pragma unroll
    for (int j = 0; j < 4; j++) {
      short s0 = t8[j];
      tv = *(__hip_bfloat16*)&s0;
      acc += __bfloat162float(tv) * (&w0.x)[j];
    }
#pragma unroll
    for (int j = 0; j < 4; j++) {
      short s1 = t8[4 + j];
      tv = *(__hip_bfloat16*)&s1;
      acc += __bfloat162float(tv) * (&w1.x)[j];
    }
  }
  float mean = acc;
#pragma unroll
  for (int o = 1; o < 16; o <<= 1) mean += __shfl_xor(mean, o);
  mean *= (1.f / 16.f);
  float d = acc - mean;
  float var = d * d;
#pragma unroll
  for (int o = 1; o < 16; o <<= 1) var += __shfl_xor(var, o);
  var *= (1.f / 16.f);
  float z = d * rsqrtf(var + 1e-5f) * g[n] + be[n];
  float t = 1.f / (1.f + expf(-z));
  T0[(size_t)bs * 16 + n] = 1.f + 0.1f * (t - 0.5f);
}

// ---------------- thp: sigmoid(gelu(LN(T0 @ thp_w^T + b))) ----------------
__global__ __launch_bounds__(256) void thp_k(const float* __restrict__ T0,
                                             const float* __restrict__ w,
                                             const float* __restrict__ bb,
                                             const float* __restrict__ g,
                                             const float* __restrict__ be,
                                             __hip_bfloat16* __restrict__ Tb,
                                             float* __restrict__ t0out) {
  __shared__ float sh[4];
  __shared__ float t0s[16];
  const int bs = blockIdx.x, tid = threadIdx.x;
  if (tid < 16) t0s[tid] = T0[(size_t)bs * 16 + tid];
  __syncthreads();
  float y[4];
#pragma unroll
  for (int i = 0; i < 4; i++) {
    int hh = tid + i * 256;
    const float* wr = w + (size_t)hh * 16;
    float a = bb[hh];
#pragma unroll
    for (int n = 0; n < 16; n++) a += t0s[n] * wr[n];
    y[i] = a;
  }
  float mean = bred_sum(y[0] + y[1] + y[2] + y[3], sh) * (1.f / 1024.f);
  float q = 0.f;
#pragma unroll
  for (int i = 0; i < 4; i++) { float d = y[i] - mean; q += d * d; }
  float var = bred_sum(q, sh) * (1.f / 1024.f);
  const float rs = rsqrtf(var + 1e-5f);
#pragma unroll
  for (int i = 0; i < 4; i++) {
    int hh = tid + i * 256;
    float z = (y[i] - mean) * rs * g[hh] + be[hh];
    float t = 1.f / (1.f + expf(-geluf(z)));
    Tb[(size_t)bs * H_ + hh] = __float2bfloat16(t);
    if (hh == 0) t0out[bs] = t;
  }
}

// ---------------- rowsum of W1b (fp32 exact) ----------------
__global__ __launch_bounds__(256) void rowsum_k(const float* __restrict__ w1,
                                                float* __restrict__ rs) {
  const int tid = threadIdx.x;
  const int row = blockIdx.x * 4 + (tid >> 6);
  const int lane = tid & 63;
  float s = 0.f;
#pragma unroll
  for (int j = 0; j < 16; j++) s += w1[(size_t)row * 2048 + 1024 + lane + j * 64];
  s = wred_sum(s);
  if (lane == 0) rs[row] = s;
}

// ---------------- fused: h = gelu(LN(...)); Ti = sig(sig(h.w2 + b2)) ----------------
__global__ __launch_bounds__(256) void hlnrd_k(const float* __restrict__ xa,
                                               const float* __restrict__ addm,
                                               const float* __restrict__ Ti,
                                               const float* __restrict__ rsum,
                                               const float* __restrict__ b1,
                                               const float* __restrict__ g,
                                               const float* __restrict__ be,
                                               const float* __restrict__ w2,
                                               const float* __restrict__ b2,
                                               float* __restrict__ tout, int mode) {
  __shared__ float sh[4];
  const int bs = blockIdx.x, tid = threadIdx.x;
  const float tv = mode ? Ti[bs] : 0.f;
  float y[4];
#pragma unroll
  for (int i = 0; i < 4; i++) {
    int hh = tid + i * 256;
    float add = mode ? tv * rsum[hh] : addm[(size_t)bs * H_ + hh];
    y[i] = xa[(size_t)bs * H_ + hh] + add + b1[hh];
  }
  float mean = bred_sum(y[0] + y[1] + y[2] + y[3], sh) * (1.f / 1024.f);
  float q = 0.f;
#pragma unroll
  for (int i = 0; i < 4; i++) { float d = y[i] - mean; q += d * d; }
  float var = bred_sum(q, sh) * (1.f / 1024.f);
  const float rs = rsqrtf(var + 1e-5f);
  float s = 0.f;
#pragma unroll
  for (int i = 0; i < 4; i++) {
    int hh = tid + i * 256;
    float z = (y[i] - mean) * rs * g[hh] + be[hh];
    s += geluf(z) * w2[hh];
  }
  s = bred_sum(s, sh);
  if (tid == 0) {
    float d = s + b2[0];
    float t = 1.f / (1.f + expf(-d));
    t = 1.f / (1.f + expf(-t));
    tout[bs] = t;
  }
}

// ---------------- global stats -> twn; also emits scale_temps output ----------------
__global__ __launch_bounds__(256) void stats_k(const float* __restrict__ t0,
                                               const float* __restrict__ t1,
                                               const float* __restrict__ t2,
                                               float* __restrict__ twn,
                                               float* __restrict__ out2) {
  __shared__ float sh[4];
  const int tid = threadIdx.x;
  float s = 0.f;
  for (int i = tid; i < BS_; i += 256) s += (t0[i] + t1[i] + t2[i]) * (1.f / 3.f);
  const float mu = bred_sum(s, sh) * (1.f / (float)BS_);
  float q = 0.f;
  for (int i = tid; i < BS_; i += 256) {
    float tw = (t0[i] + t1[i] + t2[i]) * (1.f / 3.f);
    float d = tw - mu;
    q += d * d;
  }
  const float var = bred_sum(q, sh) * (1.f / (float)BS_);
  const float stdu = sqrtf(var);
  const float inv = 1.f / (stdu + 1.1920929e-07f);
  for (int i = tid; i < BS_; i += 256) {
    float tw = (t0[i] + t1[i] + t2[i]) * (1.f / 3.f);
    twn[i] = 1.f + (tw - mu) * inv;
  }
  for (int i = tid; i < 3 * BS_; i += 256) {  // [B,3,S,1]
    int b = i / 3072, r = i - b * 3072;
    int j = r >> 10, ss = r & 1023;
    const float* tp = (j == 0) ? t0 : ((j == 1) ? t1 : t2);
    out2[i] = tp[b * S_ + ss];
  }
}

// =====================================================================
extern "C" void kernel_launch(void* const* d_in, const int* in_sizes, int n_in,
                              void* d_out, int out_size, void* d_ws, size_t ws_size,
                              hipStream_t stream) {
  (void)in_sizes; (void)n_in; (void)out_size; (void)ws_size;
  const float* x     = (const float*)d_in[0];
  const float* wq    = (const float*)d_in[1];
  const float* wk    = (const float*)d_in[2];
  const float* wv    = (const float*)d_in[3];
  const float* wo    = (const float*)d_in[4];
  const float* w_in  = (const float*)d_in[5];
  const float* w_out = (const float*)d_in[6];
  const float* wt    = (const float*)d_in[7];
  const float* ttm_g = (const float*)d_in[8];
  const float* ttm_b = (const float*)d_in[9];
  const float* thp_w = (const float*)d_in[10];
  const float* thp_b = (const float*)d_in[11];
  const float* thp_g = (const float*)d_in[12];
  const float* thp_e = (const float*)d_in[13];
  const float* w1    = (const float*)d_in[14];
  const float* b1    = (const float*)d_in[15];
  const float* tn_g  = (const float*)d_in[16];
  const float* tn_e  = (const float*)d_in[17];
  const float* w2    = (const float*)d_in[18];
  const float* b2    = (const float*)d_in[19];

  char* ws = (char*)d_ws;
  size_t off = 0;
  auto alloc = [&](size_t bytes) {
    void* p = ws + off;
    off = (off + bytes + 255) & ~(size_t)255;
    return p;
  };

  __hip_bfloat16* xb    = (__hip_bfloat16*)alloc((size_t)BS_ * H_ * 2);
  __hip_bfloat16* winb  = (__hip_bfloat16*)alloc((size_t)H3_ * H_ * 2);
  __hip_bfloat16* woutb = (__hip_bfloat16*)alloc((size_t)H_ * H_ * 2);
  __hip_bfloat16* wqkvb = (__hip_bfloat16*)alloc((size_t)H3_ * H_ * 2);
  __hip_bfloat16* wob   = (__hip_bfloat16*)alloc((size_t)H_ * H_ * 2);
  __hip_bfloat16* w1b   = (__hip_bfloat16*)alloc((size_t)H_ * 2 * H_ * 2);
  __hip_bfloat16* qkvb  = (__hip_bfloat16*)alloc((size_t)BS_ * H3_ * 2);
  __hip_bfloat16* vtb   = (__hip_bfloat16*)alloc((size_t)64 * DH_ * S_ * 2);
  __hip_bfloat16* mctxb = (__hip_bfloat16*)alloc((size_t)BS_ * H_ * 2);
  __hip_bfloat16* tob   = (__hip_bfloat16*)alloc((size_t)BS_ * H_ * 2);
  float* T0    = (float*)alloc((size_t)BS_ * NH_ * 4);
  float* xw1a  = (float*)alloc((size_t)BS_ * H_ * 4);
  float* tbw   = (float*)alloc((size_t)BS_ * H_ * 4);
  float* temps = (float*)alloc((size_t)3 * BS_ * 4);
  float* twn   = (float*)alloc((size_t)BS_ * 4);
  float* rsum  = (float*)alloc((size_t)H_ * 4);

  const float scale = 0.125f;  // DH^-0.5
  dim3 blk(256);

  // ---- all casts in one dispatch ----
  CastArgs ca;
  ca.s[0] = {x, (unsigned short*)xb, BS_ * H_, BS_ * H_};
  ca.s[1] = {w_in, (unsigned short*)winb, H3_ * H_, H3_ * H_};
  ca.s[2] = {w_out, (unsigned short*)woutb, H_ * H_, H_ * H_};
  ca.s[3] = {wq, (unsigned short*)wqkvb, H_ * H_, H_ * H_};
  ca.s[4] = {wk, (unsigned short*)wqkvb + (size_t)H_ * H_, H_ * H_, H_ * H_};
  ca.s[5] = {wv, (unsigned short*)wqkvb + (size_t)2 * H_ * H_, H_ * H_, H_ * H_};
  ca.s[6] = {wo, (unsigned short*)wob, H_ * H_, H_ * H_};
  ca.s[7] = {w1, (unsigned short*)w1b, 2 * H_ * H_, 2 * H_ * H_};
  castall_k<<<dim3((BS_ * H_ + 1023) / 1024, 8), blk, 0, stream>>>(ca);
  rowsum_k<<<H_ / 4, blk, 0, stream>>>(w1, rsum);

  // ---- ttm MHA ----
  gemm_bt<4, 4, 2, 2, true><<<dim3(H3_ / 128, BS_ / 128, 1), blk, 0, stream>>>(
      xb, winb, qkvb, H_, H_, H_, H3_, 0, 0, 0);
  transpose_v_k<<<dim3(S_ / 64, 64), blk, 0, stream>>>(qkvb, vtb);
  flash_k<true><<<dim3(64, 8), blk, 0, stream>>>(qkvb, vtb, (const float*)nullptr, mctxb, scale);
  gemm_bt<4, 4, 2, 2, true><<<dim3(H_ / 128, BS_ / 128, 1), blk, 0, stream>>>(
      mctxb, woutb, tob, H_, H_, H_, H_, 0, 0, 0);
  wtln_k<<<BS_ / 16, blk, 0, stream>>>(tob, wt, ttm_g, ttm_b, T0);
  thp_k<<<BS_, blk, 0, stream>>>(T0, thp_w, thp_b, thp_g, thp_e, tob, temps);

  // ---- temp_net (algebraic split of comb @ W1^T) ----
  gemm_bt<4, 4, 2, 2, false><<<dim3(H_ / 128, BS_ / 128, 1), blk, 0, stream>>>(
      xb, w1b, xw1a, H_, H_, 2 * H_, H_, 0, 0, 0);
  gemm_bt<4, 4, 2, 2, false><<<dim3(H_ / 128, BS_ / 128, 1), blk, 0, stream>>>(
      tob, w1b + H_, tbw, H_, H_, 2 * H_, H_, 0, 0, 0);
  hlnrd_k<<<BS_, blk, 0, stream>>>(xw1a, tbw, (const float*)nullptr, rsum, b1, tn_g, tn_e,
                                   w2, b2, temps + BS_, 0);
  hlnrd_k<<<BS_, blk, 0, stream>>>(xw1a, (const float*)nullptr, temps + BS_, rsum, b1, tn_g,
                                   tn_e, w2, b2, temps + 2 * BS_, 1);
  stats_k<<<1, blk, 0, stream>>>(temps, temps + BS_, temps + 2 * BS_, twn,
                                 (float*)d_out + (size_t)BS_ * H_);

  // ---- main attention ----
  gemm_bt<4, 4, 2, 2, true><<<dim3(H3_ / 128, BS_ / 128, 1), blk, 0, stream>>>(
      xb, wqkvb, qkvb, H_, H_, H_, H3_, 0, 0, 0);
  transpose_v_k<<<dim3(S_ / 64, 64), blk, 0, stream>>>(qkvb, vtb);
  flash_k<false><<<dim3(64, 8), blk, 0, stream>>>(qkvb, vtb, twn, mctxb, scale);
  gemm_bt<4, 4, 2, 2, false><<<dim3(H_ / 128, BS_ / 128, 1), blk, 0, stream>>>(
      mctxb, wob, (float*)d_out, H_, H_, H_, H_, 0, 0, 0);
}

// Round 5
// 445.643 us; speedup vs baseline: 1.2617x; 1.1646x over previous
//
#include <hip/hip_runtime.h>
#include <hip/hip_bf16.h>

#define DEV __device__ __forceinline__

typedef short bf16x8 __attribute__((ext_vector_type(8)));
typedef short bf16x4 __attribute__((ext_vector_type(4)));
typedef float f32x4 __attribute__((ext_vector_type(4)));

static constexpr int B_  = 4;
static constexpr int S_  = 1024;
static constexpr int H_  = 1024;
static constexpr int NH_ = 16;
static constexpr int DH_ = 64;
static constexpr int BS_ = B_ * S_;   // 4096
static constexpr int H6_ = 6 * H_;    // 6144 (merged ttm+main qkv row)

// ---------------- async global->LDS (16B per lane) ----------------
DEV void gld16(const void* g, void* l) {
  __builtin_amdgcn_global_load_lds(
      (__attribute__((address_space(1))) void*)(unsigned long long)g,
      (__attribute__((address_space(3))) void*)(unsigned)(unsigned long long)l,
      16, 0, 0);
}

// 16x16x16 bf16 MFMA (A-frag layout matches C-layout of transposed scores)
DEV f32x4 pv_mfma(bf16x4 a, bf16x4 b, f32x4 c) {
#if __has_builtin(__builtin_amdgcn_mfma_f32_16x16x16bf16_1k)
  return __builtin_amdgcn_mfma_f32_16x16x16bf16_1k(a, b, c, 0, 0, 0);
#else
  asm volatile("v_mfma_f32_16x16x16_bf16 %0, %1, %2, %0" : "+v"(c) : "v"(a), "v"(b));
  return c;
#endif
}

// ---------------- reductions (blockDim == 256) ----------------
DEV float wred_sum(float v) {
#pragma unroll
  for (int o = 32; o; o >>= 1) v += __shfl_xor(v, o);
  return v;
}
DEV float bred_sum(float v, float* sh) {
  v = wred_sum(v);
  const int tid = threadIdx.x;
  if ((tid & 63) == 0) sh[tid >> 6] = v;
  __syncthreads();
  v = sh[0] + sh[1] + sh[2] + sh[3];
  __syncthreads();
  return v;
}
DEV float geluf(float x) { return 0.5f * x * (1.f + erff(x * 0.70710678118654752f)); }

// ---------------- fused casts: all fp32->bf16 staging in ONE dispatch ----------------
struct CastSeg { const float* src; unsigned short* dst; int n; };
struct CastArgs { CastSeg s[7]; };
__global__ __launch_bounds__(256) void castall_k(CastArgs a) {
  const CastSeg g = a.s[blockIdx.y];
  int i = (blockIdx.x * 256 + threadIdx.x) * 4;
  if (i >= g.n) return;
  float4 v = *(const float4*)(g.src + i);
  __hip_bfloat16 o0 = __float2bfloat16(v.x), o1 = __float2bfloat16(v.y);
  __hip_bfloat16 o2 = __float2bfloat16(v.z), o3 = __float2bfloat16(v.w);
  ushort4 o;
  o.x = *(unsigned short*)&o0; o.y = *(unsigned short*)&o1;
  o.z = *(unsigned short*)&o2; o.w = *(unsigned short*)&o3;
  *(ushort4*)(g.dst + i) = o;
}

// ---------------- weff[n,h] = sum_o wt[n,o] * wout[o,h]  (fp32, atomic combine) ----------------
__global__ __launch_bounds__(256) void weff_k(const float* __restrict__ wt,
                                              const float* __restrict__ wout,
                                              float* __restrict__ weff) {
  const int j = blockIdx.x;   // h block of 64 (16 blocks)
  const int oc = blockIdx.y;  // o chunk of 256 (4 chunks)
  const int tid = threadIdx.x, hl = tid & 63, ng = tid >> 6;
  const int h = j * 64 + hl;
  float acc[4] = {0.f, 0.f, 0.f, 0.f};
  for (int o = oc * 256; o < oc * 256 + 256; o++) {
    float wv = wout[(size_t)o * H_ + h];
#pragma unroll
    for (int i = 0; i < 4; i++) acc[i] += wt[(size_t)(ng * 4 + i) * H_ + o] * wv;
  }
#pragma unroll
  for (int i = 0; i < 4; i++) atomicAdd(&weff[(size_t)(ng * 4 + i) * H_ + h], acc[i]);
}

// ---------------- MFMA GEMM: C[M,N] = A[M,K] * W[N,K]^T ----------------
// MID: A switches to Ap2 at k>=kmid; partial acc written to Cmid at k==kmid.
template <int MT, int NT, int WR, int WC, bool OBF, bool MID>
__global__ __launch_bounds__(256) void gemm_bt(
    const __hip_bfloat16* __restrict__ Ap, const __hip_bfloat16* __restrict__ Wp,
    void* __restrict__ Cp, int K, int lda, int ldw, int ldc,
    const __hip_bfloat16* __restrict__ Ap2, float* __restrict__ Cmid, int kmid) {
  constexpr int BM = WR * MT * 16;
  constexpr int BN = WC * NT * 16;
  constexpr int BK = 32;
  __shared__ __align__(16) short sA[BM * BK];
  __shared__ __align__(16) short sB[BN * BK];
  const int tid = threadIdx.x;
  const int wave = tid >> 6, lane = tid & 63;
  const int wm = wave / WC, wn = wave % WC;
  const int lr = lane & 15, kq = lane >> 4;
  const short* Ab = (const short*)Ap + (long long)blockIdx.y * BM * lda;
  const short* Ab2 = MID ? (const short*)Ap2 + (long long)blockIdx.y * BM * lda : nullptr;
  const short* Wb = (const short*)Wp + (long long)blockIdx.x * BN * ldw;
  const long long row0 = (long long)blockIdx.y * BM + wm * MT * 16 + kq * 4;
  const long long col0 = (long long)blockIdx.x * BN + wn * NT * 16 + lr;

  f32x4 acc[MT][NT];
#pragma unroll
  for (int i = 0; i < MT; i++)
#pragma unroll
    for (int j = 0; j < NT; j++) acc[i][j] = f32x4{0.f, 0.f, 0.f, 0.f};

  for (int k0 = 0; k0 < K; k0 += BK) {
    const short* Asrc;
    int ka;
    if (MID && k0 >= kmid) { Asrc = Ab2; ka = k0 - kmid; }
    else { Asrc = Ab; ka = k0; }
#pragma unroll
    for (int r = 0; r < BM / 64; r++) {
      int idx = r * 256 + tid;
      const short* src = Asrc + (long long)(idx >> 2) * lda + ka + (idx & 3) * 8;
      gld16(src, sA + (size_t)idx * 8);
    }
#pragma unroll
    for (int r = 0; r < BN / 64; r++) {
      int idx = r * 256 + tid;
      const short* src = Wb + (long long)(idx >> 2) * ldw + k0 + (idx & 3) * 8;
      gld16(src, sB + (size_t)idx * 8);
    }
    __syncthreads();
    bf16x8 af[MT], bfr[NT];
#pragma unroll
    for (int i = 0; i < MT; i++)
      af[i] = *(const bf16x8*)(sA + (wm * MT * 16 + i * 16 + lr) * BK + kq * 8);
#pragma unroll
    for (int j = 0; j < NT; j++)
      bfr[j] = *(const bf16x8*)(sB + (wn * NT * 16 + j * 16 + lr) * BK + kq * 8);
#pragma unroll
    for (int i = 0; i < MT; i++)
#pragma unroll
      for (int j = 0; j < NT; j++)
        acc[i][j] = __builtin_amdgcn_mfma_f32_16x16x32_bf16(af[i], bfr[j], acc[i][j], 0, 0, 0);
    if constexpr (MID) {
      if (k0 + BK == kmid) {
#pragma unroll
        for (int i = 0; i < MT; i++)
#pragma unroll
          for (int j = 0; j < NT; j++)
#pragma unroll
            for (int r = 0; r < 4; r++)
              Cmid[(row0 + i * 16 + r) * ldc + col0 + j * 16] = acc[i][j][r];
      }
    }
    __syncthreads();
  }
#pragma unroll
  for (int i = 0; i < MT; i++)
#pragma unroll
    for (int j = 0; j < NT; j++)
#pragma unroll
      for (int r = 0; r < 4; r++) {
        long long off = (row0 + i * 16 + r) * ldc + col0 + j * 16;
        if constexpr (OBF)
          ((__hip_bfloat16*)Cp)[off] = __float2bfloat16(acc[i][j][r]);
        else
          ((float*)Cp)[off] = acc[i][j][r];
      }
}

// ---------------- V transpose (both attentions): vt2[bh2][d][s] ----------------
__global__ __launch_bounds__(256) void transpose_v2_k(const __hip_bfloat16* __restrict__ qkv2,
                                                      __hip_bfloat16* __restrict__ vt2) {
  const int bh2 = blockIdx.y;           // 0..127 (0-63 ttm, 64-127 main)
  const int sel = bh2 >> 6, b = (bh2 >> 4) & 3, h = bh2 & 15;
  const int s0 = blockIdx.x << 6;
  __shared__ short tile[64 * 65];
  const int tid = threadIdx.x;
  const short* src = (const short*)qkv2 + ((size_t)(b * S_) + s0) * H6_ + sel * 3 * H_ +
                     2 * H_ + h * DH_;
#pragma unroll
  for (int i = 0; i < 4; i++) {
    int idx = tid + i * 256;
    int rr = idx >> 4, c4 = (idx & 15) * 4;
    short4 v = *(const short4*)(src + (size_t)rr * H6_ + c4);
    tile[(c4 + 0) * 65 + rr] = v.x;
    tile[(c4 + 1) * 65 + rr] = v.y;
    tile[(c4 + 2) * 65 + rr] = v.z;
    tile[(c4 + 3) * 65 + rr] = v.w;
  }
  __syncthreads();
  short* dst = (short*)vt2 + (size_t)bh2 * DH_ * S_ + s0;
#pragma unroll
  for (int i = 0; i < 4; i++) {
    int idx = tid + i * 256;
    int dd = idx >> 4, s4 = (idx & 15) * 4;
    short4 o;
    o.x = tile[dd * 65 + s4 + 0];
    o.y = tile[dd * 65 + s4 + 1];
    o.z = tile[dd * 65 + s4 + 2];
    o.w = tile[dd * 65 + s4 + 3];
    *(short4*)(dst + (size_t)dd * S_ + s4) = o;
  }
}

// ---------------- fused flash attention ----------------
template <bool TTM>
__global__ __launch_bounds__(256) void flash_k(
    const __hip_bfloat16* __restrict__ qkvB,  // base already offset to this attn's q
    const __hip_bfloat16* __restrict__ vt,    // [bh][DH][S] for this attn
    const float* __restrict__ twn,
    __hip_bfloat16* __restrict__ ctx,         // [B,S,H]
    float scale, int ldq) {
  __shared__ __align__(16) short sK[2][128 * 64];
  __shared__ __align__(16) short sVT[2][64 * 128];
  const int bh = blockIdx.x, b = bh >> 4, h = bh & 15;
  const int qb = blockIdx.y;
  const int tid = threadIdx.x, lane = tid & 63, wid = tid >> 6;
  const int lr = lane & 15, quad = lane >> 4;
  const short* qg = (const short*)qkvB + ((size_t)(b * S_) + qb * 128) * ldq + h * 64;
  const short* kg = (const short*)qkvB + (size_t)b * S_ * ldq + H_ + h * 64;
  const short* vg = (const short*)vt + (size_t)bh * DH_ * S_;

  auto stage = [&](int kt, int buf) {
#pragma unroll
    for (int i = 0; i < 4; i++) {
      int idx = i * 256 + tid;
      int row = idx >> 3, cp = idx & 7;
      int c = cp ^ (row & 7);
      gld16(kg + (size_t)(kt * 128 + row) * ldq + c * 8, &sK[buf][(size_t)idx * 8]);
    }
#pragma unroll
    for (int i = 0; i < 4; i++) {
      int idx = i * 256 + tid;
      int row = idx >> 4, cp = idx & 15;
      int c = cp ^ (row & 15);
      gld16(vg + (size_t)row * S_ + kt * 128 + c * 8, &sVT[buf][(size_t)idx * 8]);
    }
  };

  bf16x8 bq[2][2];
#pragma unroll
  for (int nt = 0; nt < 2; nt++)
#pragma unroll
    for (int kk = 0; kk < 2; kk++)
      bq[nt][kk] =
          *(const bf16x8*)(qg + (size_t)(wid * 32 + nt * 16 + lr) * ldq + kk * 32 + quad * 8);

  float fs[2];
#pragma unroll
  for (int nt = 0; nt < 2; nt++) {
    int q = qb * 128 + wid * 32 + nt * 16 + lr;
    fs[nt] = TTM ? scale : scale * twn[b * S_ + q];
  }
  f32x4 O[2][4];
#pragma unroll
  for (int nt = 0; nt < 2; nt++)
#pragma unroll
    for (int dt = 0; dt < 4; dt++) O[nt][dt] = f32x4{0.f, 0.f, 0.f, 0.f};
  float mrow[2] = {-INFINITY, -INFINITY};
  float lrow[2] = {0.f, 0.f};

  stage(0, 0);
  __syncthreads();

  for (int kt = 0; kt < 8; kt++) {
    const int cur = kt & 1;
    if (kt < 7) stage(kt + 1, cur ^ 1);
    const short* sKc = sK[cur];
    const short* sVc = sVT[cur];

    f32x4 Sa[8][2];
#pragma unroll
    for (int mt = 0; mt < 8; mt++)
#pragma unroll
      for (int nt = 0; nt < 2; nt++) Sa[mt][nt] = f32x4{0.f, 0.f, 0.f, 0.f};
#pragma unroll
    for (int mt = 0; mt < 8; mt++)
#pragma unroll
      for (int kk = 0; kk < 2; kk++) {
        int row = mt * 16 + lr;
        int cp = (kk * 4 + quad) ^ (lr & 7);
        bf16x8 ak = *(const bf16x8*)(sKc + row * 64 + cp * 8);
#pragma unroll
        for (int nt = 0; nt < 2; nt++)
          Sa[mt][nt] = __builtin_amdgcn_mfma_f32_16x16x32_bf16(ak, bq[nt][kk], Sa[mt][nt], 0, 0, 0);
      }

    bf16x4 Pf[8][2];
#pragma unroll
    for (int nt = 0; nt < 2; nt++) {
      float mx = -INFINITY;
#pragma unroll
      for (int mt = 0; mt < 8; mt++)
#pragma unroll
        for (int r = 0; r < 4; r++) {
          Sa[mt][nt][r] *= fs[nt];
          mx = fmaxf(mx, Sa[mt][nt][r]);
        }
      mx = fmaxf(mx, __shfl_xor(mx, 16));
      mx = fmaxf(mx, __shfl_xor(mx, 32));
      const float mnew = fmaxf(mrow[nt], mx);
      const float al = __expf(mrow[nt] - mnew);
      mrow[nt] = mnew;
      float ls = 0.f;
#pragma unroll
      for (int mt = 0; mt < 8; mt++) {
        float p0 = __expf(Sa[mt][nt][0] - mnew);
        float p1 = __expf(Sa[mt][nt][1] - mnew);
        float p2 = __expf(Sa[mt][nt][2] - mnew);
        float p3 = __expf(Sa[mt][nt][3] - mnew);
        ls += (p0 + p1) + (p2 + p3);
        __hip_bfloat16 h0 = __float2bfloat16(p0), h1 = __float2bfloat16(p1);
        __hip_bfloat16 h2 = __float2bfloat16(p2), h3 = __float2bfloat16(p3);
        bf16x4 pk;
        pk[0] = *(short*)&h0; pk[1] = *(short*)&h1;
        pk[2] = *(short*)&h2; pk[3] = *(short*)&h3;
        Pf[mt][nt] = pk;
      }
      ls += __shfl_xor(ls, 16);
      ls += __shfl_xor(ls, 32);
      lrow[nt] = lrow[nt] * al + ls;
#pragma unroll
      for (int r = 0; r < 4; r++) {
        float ar = __shfl(al, quad * 4 + r);
#pragma unroll
        for (int dt = 0; dt < 4; dt++) O[nt][dt][r] *= ar;
      }
    }

#pragma unroll
    for (int mt = 0; mt < 8; mt++)
#pragma unroll
      for (int dt = 0; dt < 4; dt++) {
        int row = dt * 16 + lr;
        int cp = (2 * mt + (quad >> 1)) ^ lr;
        bf16x4 bv = *(const bf16x4*)(sVc + row * 128 + cp * 8 + (quad & 1) * 4);
#pragma unroll
        for (int nt = 0; nt < 2; nt++) O[nt][dt] = pv_mfma(Pf[mt][nt], bv, O[nt][dt]);
      }

    __syncthreads();
  }

#pragma unroll
  for (int nt = 0; nt < 2; nt++)
#pragma unroll
    for (int r = 0; r < 4; r++) {
      float li = __shfl(lrow[nt], quad * 4 + r);
      float inv = 1.f / li;
      int q = qb * 128 + wid * 32 + nt * 16 + quad * 4 + r;
      __hip_bfloat16* op = ctx + ((size_t)(b * S_) + q) * H_ + h * 64 + lr;
#pragma unroll
      for (int dt = 0; dt < 4; dt++)
        op[dt * 16] = __float2bfloat16(O[nt][dt][r] * inv);
    }
}

// ---------------- MFMA wt-projection + LN(16) + sigmoid -> T0 ----------------
// block = 16 bs rows; 4 waves split K=1024; weff stays fp32 (cvt per-frag).
__global__ __launch_bounds__(256) void wtproj_k(const __hip_bfloat16* __restrict__ mctx,
                                                const float* __restrict__ weff,
                                                const float* __restrict__ g,
                                                const float* __restrict__ be,
                                                float* __restrict__ T0) {
  __shared__ float sC[4][256];
  const int tid = threadIdx.x, lane = tid & 63, wid = tid >> 6;
  const int lr = lane & 15, quad = lane >> 4;
  const int bs0 = blockIdx.x * 16;
  const short* aG = (const short*)mctx + (size_t)(bs0 + lr) * H_ + wid * 256;
  const float* bG = weff + (size_t)lr * H_ + wid * 256;
  f32x4 acc = f32x4{0.f, 0.f, 0.f, 0.f};
#pragma unroll
  for (int it = 0; it < 8; it++) {
    bf16x8 a = *(const bf16x8*)(aG + it * 32 + quad * 8);
    float4 b0 = *(const float4*)(bG + it * 32 + quad * 8);
    float4 b1 = *(const float4*)(bG + it * 32 + quad * 8 + 4);
    bf16x8 bb;
#pragma unroll
    for (int j = 0; j < 4; j++) {
      __hip_bfloat16 c0 = __float2bfloat16((&b0.x)[j]);
      __hip_bfloat16 c1 = __float2bfloat16((&b1.x)[j]);
      bb[j] = *(short*)&c0;
      bb[4 + j] = *(short*)&c1;
    }
    acc = __builtin_amdgcn_mfma_f32_16x16x32_bf16(a, bb, acc, 0, 0, 0);
  }
#pragma unroll
  for (int r = 0; r < 4; r++) sC[wid][(quad * 4 + r) * 16 + lr] = acc[r];
  __syncthreads();
  float tot = sC[0][tid] + sC[1][tid] + sC[2][tid] + sC[3][tid];
  const int n = tid & 15;
  float mean = tot;
#pragma unroll
  for (int o = 1; o < 16; o <<= 1) mean += __shfl_xor(mean, o);
  mean *= (1.f / 16.f);
  float d = tot - mean;
  float var = d * d;
#pragma unroll
  for (int o = 1; o < 16; o <<= 1) var += __shfl_xor(var, o);
  var *= (1.f / 16.f);
  float z = d * rsqrtf(var + 1e-5f) * g[n] + be[n];
  float t = 1.f / (1.f + expf(-z));
  T0[(size_t)blockIdx.x * 256 + tid] = 1.f + 0.1f * (t - 0.5f);
}

// ---------------- thp: sigmoid(gelu(LN(T0 @ thp_w^T + b))) ----------------
__global__ __launch_bounds__(256) void thp_k(const float* __restrict__ T0,
                                             const float* __restrict__ w,
                                             const float* __restrict__ bb,
                                             const float* __restrict__ g,
                                             const float* __restrict__ be,
                                             __hip_bfloat16* __restrict__ Tb,
                                             float* __restrict__ t0out) {
  __shared__ float sh[4];
  __shared__ float t0s[16];
  const int bs = blockIdx.x, tid = threadIdx.x;
  if (tid < 16) t0s[tid] = T0[(size_t)bs * 16 + tid];
  __syncthreads();
  float y[4];
#pragma unroll
  for (int i = 0; i < 4; i++) {
    int hh = tid + i * 256;
    const float* wr = w + (size_t)hh * 16;
    float a = bb[hh];
#pragma unroll
    for (int n = 0; n < 16; n++) a += t0s[n] * wr[n];
    y[i] = a;
  }
  float mean = bred_sum(y[0] + y[1] + y[2] + y[3], sh) * (1.f / 1024.f);
  float q = 0.f;
#pragma unroll
  for (int i = 0; i < 4; i++) { float d = y[i] - mean; q += d * d; }
  float var = bred_sum(q, sh) * (1.f / 1024.f);
  const float rs = rsqrtf(var + 1e-5f);
#pragma unroll
  for (int i = 0; i < 4; i++) {
    int hh = tid + i * 256;
    float z = (y[i] - mean) * rs * g[hh] + be[hh];
    float t = 1.f / (1.f + expf(-geluf(z)));
    Tb[(size_t)bs * H_ + hh] = __float2bfloat16(t);
    if (hh == 0) t0out[bs] = t;
  }
}

// ---------------- rowsum of W1b (fp32 exact) ----------------
__global__ __launch_bounds__(256) void rowsum_k(const float* __restrict__ w1,
                                                float* __restrict__ rs) {
  const int tid = threadIdx.x;
  const int row = blockIdx.x * 4 + (tid >> 6);
  const int lane = tid & 63;
  float s = 0.f;
#pragma unroll
  for (int j = 0; j < 16; j++) s += w1[(size_t)row * 2048 + 1024 + lane + j * 64];
  s = wred_sum(s);
  if (lane == 0) rs[row] = s;
}

// ---------------- fused: h = gelu(LN(y)); Ti = sig(sig(h.w2 + b2)) ----------------
// mode0: y = addm + b1 (addm already = xw1a + tbw).  mode1: y = xa + Ti*rsum + b1.
__global__ __launch_bounds__(256) void hlnrd_k(const float* __restrict__ xa,
                                               const float* __restrict__ addm,
                                               const float* __restrict__ Ti,
                                               const float* __restrict__ rsum,
                                               const float* __restrict__ b1,
                                               const float* __restrict__ g,
                                               const float* __restrict__ be,
                                               const float* __restrict__ w2,
                                               const float* __restrict__ b2,
                                               float* __restrict__ tout, int mode) {
  __shared__ float sh[4];
  const int bs = blockIdx.x, tid = threadIdx.x;
  const float tv = mode ? Ti[bs] : 0.f;
  float y[4];
#pragma unroll
  for (int i = 0; i < 4; i++) {
    int hh = tid + i * 256;
    float v = mode ? (xa[(size_t)bs * H_ + hh] + tv * rsum[hh])
                   : addm[(size_t)bs * H_ + hh];
    y[i] = v + b1[hh];
  }
  float mean = bred_sum(y[0] + y[1] + y[2] + y[3], sh) * (1.f / 1024.f);
  float q = 0.f;
#pragma unroll
  for (int i = 0; i < 4; i++) { float d = y[i] - mean; q += d * d; }
  float var = bred_sum(q, sh) * (1.f / 1024.f);
  const float rs = rsqrtf(var + 1e-5f);
  float s = 0.f;
#pragma unroll
  for (int i = 0; i < 4; i++) {
    int hh = tid + i * 256;
    float z = (y[i] - mean) * rs * g[hh] + be[hh];
    s += geluf(z) * w2[hh];
  }
  s = bred_sum(s, sh);
  if (tid == 0) {
    float d = s + b2[0];
    float t = 1.f / (1.f + expf(-d));
    t = 1.f / (1.f + expf(-t));
    tout[bs] = t;
  }
}

// ---------------- global stats -> twn; also emits scale_temps output ----------------
__global__ __launch_bounds__(256) void stats_k(const float* __restrict__ t0,
                                               const float* __restrict__ t1,
                                               const float* __restrict__ t2,
                                               float* __restrict__ twn,
                                               float* __restrict__ out2) {
  __shared__ float sh[4];
  const int tid = threadIdx.x;
  float s = 0.f;
  for (int i = tid; i < BS_; i += 256) s += (t0[i] + t1[i] + t2[i]) * (1.f / 3.f);
  const float mu = bred_sum(s, sh) * (1.f / (float)BS_);
  float q = 0.f;
  for (int i = tid; i < BS_; i += 256) {
    float tw = (t0[i] + t1[i] + t2[i]) * (1.f / 3.f);
    float d = tw - mu;
    q += d * d;
  }
  const float var = bred_sum(q, sh) * (1.f / (float)BS_);
  const float stdu = sqrtf(var);
  const float inv = 1.f / (stdu + 1.1920929e-07f);
  for (int i = tid; i < BS_; i += 256) {
    float tw = (t0[i] + t1[i] + t2[i]) * (1.f / 3.f);
    twn[i] = 1.f + (tw - mu) * inv;
  }
  for (int i = tid; i < 3 * BS_; i += 256) {
    int b = i / 3072, r = i - b * 3072;
    int j = r >> 10, ss = r & 1023;
    const float* tp = (j == 0) ? t0 : ((j == 1) ? t1 : t2);
    out2[i] = tp[b * S_ + ss];
  }
}

// =====================================================================
extern "C" void kernel_launch(void* const* d_in, const int* in_sizes, int n_in,
                              void* d_out, int out_size, void* d_ws, size_t ws_size,
                              hipStream_t stream) {
  (void)in_sizes; (void)n_in; (void)out_size; (void)ws_size;
  const float* x     = (const float*)d_in[0];
  const float* wq    = (const float*)d_in[1];
  const float* wk    = (const float*)d_in[2];
  const float* wv    = (const float*)d_in[3];
  const float* wo    = (const float*)d_in[4];
  const float* w_in  = (const float*)d_in[5];
  const float* w_out = (const float*)d_in[6];
  const float* wt    = (const float*)d_in[7];
  const float* ttm_g = (const float*)d_in[8];
  const float* ttm_b = (const float*)d_in[9];
  const float* thp_w = (const float*)d_in[10];
  const float* thp_b = (const float*)d_in[11];
  const float* thp_g = (const float*)d_in[12];
  const float* thp_e = (const float*)d_in[13];
  const float* w1    = (const float*)d_in[14];
  const float* b1    = (const float*)d_in[15];
  const float* tn_g  = (const float*)d_in[16];
  const float* tn_e  = (const float*)d_in[17];
  const float* w2    = (const float*)d_in[18];
  const float* b2    = (const float*)d_in[19];

  char* ws = (char*)d_ws;
  size_t off = 0;
  auto alloc = [&](size_t bytes) {
    void* p = ws + off;
    off = (off + bytes + 255) & ~(size_t)255;
    return p;
  };

  __hip_bfloat16* xb    = (__hip_bfloat16*)alloc((size_t)BS_ * H_ * 2);
  __hip_bfloat16* wcat  = (__hip_bfloat16*)alloc((size_t)H6_ * H_ * 2);  // [w_in; wq; wk; wv]
  __hip_bfloat16* wob   = (__hip_bfloat16*)alloc((size_t)H_ * H_ * 2);
  __hip_bfloat16* w1b   = (__hip_bfloat16*)alloc((size_t)H_ * 2 * H_ * 2);
  __hip_bfloat16* qkv2  = (__hip_bfloat16*)alloc((size_t)BS_ * H6_ * 2);  // [ttm qkv | main qkv]
  __hip_bfloat16* vt2   = (__hip_bfloat16*)alloc((size_t)128 * DH_ * S_ * 2);
  __hip_bfloat16* mctxb = (__hip_bfloat16*)alloc((size_t)BS_ * H_ * 2);
  __hip_bfloat16* tob   = (__hip_bfloat16*)alloc((size_t)BS_ * H_ * 2);  // T_base bf16
  float* weff  = (float*)alloc((size_t)NH_ * H_ * 4);
  float* T0    = (float*)alloc((size_t)BS_ * NH_ * 4);
  float* xw1a  = (float*)alloc((size_t)BS_ * H_ * 4);
  float* tbw   = (float*)alloc((size_t)BS_ * H_ * 4);  // xw1a + Tb@W1b^T
  float* temps = (float*)alloc((size_t)3 * BS_ * 4);
  float* twn   = (float*)alloc((size_t)BS_ * 4);
  float* rsum  = (float*)alloc((size_t)H_ * 4);

  const float scale = 0.125f;  // DH^-0.5
  dim3 blk(256);

  // ---- staging: casts (1 dispatch), weff (zero + accumulate), rowsum ----
  CastArgs ca;
  ca.s[0] = {x, (unsigned short*)xb, BS_ * H_};
  ca.s[1] = {w_in, (unsigned short*)wcat, 3 * H_ * H_};
  ca.s[2] = {wq, (unsigned short*)wcat + (size_t)3 * H_ * H_, H_ * H_};
  ca.s[3] = {wk, (unsigned short*)wcat + (size_t)4 * H_ * H_, H_ * H_};
  ca.s[4] = {wv, (unsigned short*)wcat + (size_t)5 * H_ * H_, H_ * H_};
  ca.s[5] = {wo, (unsigned short*)wob, H_ * H_};
  ca.s[6] = {w1, (unsigned short*)w1b, 2 * H_ * H_};
  castall_k<<<dim3((BS_ * H_ + 1023) / 1024, 7), blk, 0, stream>>>(ca);
  hipMemsetAsync(weff, 0, (size_t)NH_ * H_ * 4, stream);
  weff_k<<<dim3(16, 4), blk, 0, stream>>>(wt, w_out, weff);
  rowsum_k<<<H_ / 4, blk, 0, stream>>>(w1, rsum);

  // ---- one merged qkv GEMM for both attentions (N=6144) ----
  gemm_bt<4, 4, 2, 2, true, false><<<dim3(H6_ / 128, BS_ / 128), blk, 0, stream>>>(
      xb, wcat, qkv2, H_, H_, H_, H6_, nullptr, nullptr, 0);
  transpose_v2_k<<<dim3(S_ / 64, 128), blk, 0, stream>>>(qkv2, vt2);

  // ---- ttm attention -> mctx; wt-projection (weff) -> T0; thp -> T_base ----
  flash_k<true><<<dim3(64, 8), blk, 0, stream>>>(qkv2, vt2, (const float*)nullptr, mctxb,
                                                 scale, H6_);
  wtproj_k<<<BS_ / 16, blk, 0, stream>>>(mctxb, weff, ttm_g, ttm_b, T0);
  thp_k<<<BS_, blk, 0, stream>>>(T0, thp_w, thp_b, thp_g, thp_e, tob, temps);

  // ---- temp_net: one dual-A GEMM (K=2048), xw1a written at k=1024 ----
  gemm_bt<4, 2, 2, 2, false, true><<<dim3(H_ / 64, BS_ / 128), blk, 0, stream>>>(
      xb, w1b, tbw, 2 * H_, H_, 2 * H_, H_, tob, xw1a, H_);
  hlnrd_k<<<BS_, blk, 0, stream>>>(xw1a, tbw, (const float*)nullptr, rsum, b1, tn_g, tn_e,
                                   w2, b2, temps + BS_, 0);
  hlnrd_k<<<BS_, blk, 0, stream>>>(xw1a, (const float*)nullptr, temps + BS_, rsum, b1, tn_g,
                                   tn_e, w2, b2, temps + 2 * BS_, 1);
  stats_k<<<1, blk, 0, stream>>>(temps, temps + BS_, temps + 2 * BS_, twn,
                                 (float*)d_out + (size_t)BS_ * H_);

  // ---- main attention + out-proj ----
  flash_k<false><<<dim3(64, 8), blk, 0, stream>>>(qkv2 + 3 * H_,
                                                  vt2 + (size_t)64 * DH_ * S_, twn, mctxb,
                                                  scale, H6_);
  gemm_bt<4, 2, 2, 2, false, false><<<dim3(H_ / 64, BS_ / 128), blk, 0, stream>>>(
      mctxb, wob, (float*)d_out, H_, H_, H_, H_, nullptr, nullptr, 0);
}